// Round 7
// baseline (2236.235 us; speedup 1.0000x reference)
//
#include <hip/hip_runtime.h>
#include <cstddef>
#include <cstdint>

// Problem constants
#define kB 32
#define kT 2048
#define kIn 512
#define kH 256
#define kBeta 0.85f
#define kThr 1.0f

// Block layout: blocks [0, N_SCAN) = scan (one batch each, 256 thr, 4 waves),
// blocks [N_SCAN, N_SCAN + N_GEMM) = GEMM tiles (128x256, t-major order).
#define N_SCAN kB
#define GEMM_TM 128
#define N_TILES (kT / GEMM_TM)      // 16 tiles per batch
#define N_GEMM (kB * N_TILES)       // 512 gemm blocks
#define FLAGS_PER_B N_TILES
#define TBURST 8

// GEMM LDS strides (floats): +4 pads keep 16B row alignment, 2-way-max banks
#define ALD 132                     // 128+4
#define BLD 260                     // 256+4
#define SMEM_FLOATS (16 * ALD + 16 * BLD)   // 6272 floats = 25.1 KB (scan: 8 KB)

__device__ __forceinline__ void wait_flag(int* f) {
    // acquire/agent: later proj loads must see the producer XCD's stores
    while (__hip_atomic_load(f, __ATOMIC_ACQUIRE, __HIP_MEMORY_SCOPE_AGENT) == 0) {
        __builtin_amdgcn_s_sleep(2);
    }
}

// ---------------------------------------------------------------------------
// GEMM body: 256 threads, 128x256 tile: proj = x @ W_in^T + b_in, flag publish.
// Ascending-k fmaf chain per output element: proj bit-identical to rounds 1-6.
// ---------------------------------------------------------------------------
__device__ void gemm_body(const float* __restrict__ A,
                          const float* __restrict__ W,
                          const float* __restrict__ bias,
                          float* __restrict__ P,
                          int* flags, int gid, float* smem)
{
    float* As = smem;               // [16][ALD]
    float* Bs = smem + 16 * ALD;    // [16][BLD]
    const int tid = threadIdx.x;
    const int b  = gid & 31;        // t-major: all batches' tile tt first
    const int tt = gid >> 5;        // 0..15
    const int bm = b * kT + tt * GEMM_TM;
    const int tx = tid & 15;        // n-dir
    const int ty = tid >> 4;        // m-dir

    float acc[8][16];
#pragma unroll
    for (int i = 0; i < 8; ++i)
#pragma unroll
        for (int j = 0; j < 16; ++j) acc[i][j] = 0.f;

    // A staging: 512 float4 chunks (128 rows x 16k), 2/thread
    const int ra0 = tid >> 2,          ka0 = (tid & 3) << 2;
    const int ra1 = (tid + 256) >> 2,  ka1 = (tid & 3) << 2;  // rows 64..127
    // W staging: 1024 float4 chunks (256 rows x 16k), 4/thread

    for (int kb = 0; kb < kIn; kb += 16) {
        const float4 a0 = *reinterpret_cast<const float4*>(A + (size_t)(bm + ra0) * kIn + kb + ka0);
        const float4 a1 = *reinterpret_cast<const float4*>(A + (size_t)(bm + ra1) * kIn + kb + ka1);
        float4 wv[4];
#pragma unroll
        for (int j = 0; j < 4; ++j) {
            const int c = tid + 256 * j;
            wv[j] = *reinterpret_cast<const float4*>(W + (size_t)(c >> 2) * kIn + kb + ((c & 3) << 2));
        }
        __syncthreads();   // previous iteration's LDS reads done
        As[(ka0 + 0) * ALD + ra0] = a0.x;
        As[(ka0 + 1) * ALD + ra0] = a0.y;
        As[(ka0 + 2) * ALD + ra0] = a0.z;
        As[(ka0 + 3) * ALD + ra0] = a0.w;
        As[(ka1 + 0) * ALD + ra1] = a1.x;
        As[(ka1 + 1) * ALD + ra1] = a1.y;
        As[(ka1 + 2) * ALD + ra1] = a1.z;
        As[(ka1 + 3) * ALD + ra1] = a1.w;
#pragma unroll
        for (int j = 0; j < 4; ++j) {
            const int c = tid + 256 * j;
            const int rw = c >> 2, kw = (c & 3) << 2;
            Bs[(kw + 0) * BLD + rw] = wv[j].x;
            Bs[(kw + 1) * BLD + rw] = wv[j].y;
            Bs[(kw + 2) * BLD + rw] = wv[j].z;
            Bs[(kw + 3) * BLD + rw] = wv[j].w;
        }
        __syncthreads();

#pragma unroll
        for (int k = 0; k < 16; ++k) {
            const float4 aa0 = *reinterpret_cast<const float4*>(&As[k * ALD + ty * 4]);
            const float4 aa1 = *reinterpret_cast<const float4*>(&As[k * ALD + ty * 4 + 64]);
            float av8[8] = {aa0.x, aa0.y, aa0.z, aa0.w, aa1.x, aa1.y, aa1.z, aa1.w};
            float bv16[16];
#pragma unroll
            for (int g = 0; g < 4; ++g) {
                const float4 bb = *reinterpret_cast<const float4*>(&Bs[k * BLD + tx * 4 + g * 64]);
                bv16[g * 4 + 0] = bb.x; bv16[g * 4 + 1] = bb.y;
                bv16[g * 4 + 2] = bb.z; bv16[g * 4 + 3] = bb.w;
            }
#pragma unroll
            for (int i = 0; i < 8; ++i)
#pragma unroll
                for (int j = 0; j < 16; ++j)
                    acc[i][j] = fmaf(av8[i], bv16[j], acc[i][j]);
        }
    }

    float4 bl[4];
#pragma unroll
    for (int g = 0; g < 4; ++g)
        bl[g] = *reinterpret_cast<const float4*>(bias + tx * 4 + g * 64);
#pragma unroll
    for (int i = 0; i < 8; ++i) {
        const int m = bm + ty * 4 + (i & 3) + ((i >> 2) << 6);
#pragma unroll
        for (int g = 0; g < 4; ++g) {
            float4 o;
            o.x = acc[i][g * 4 + 0] + bl[g].x;
            o.y = acc[i][g * 4 + 1] + bl[g].y;
            o.z = acc[i][g * 4 + 2] + bl[g].z;
            o.w = acc[i][g * 4 + 3] + bl[g].w;
            *reinterpret_cast<float4*>(P + (size_t)m * kH + tx * 4 + g * 64) = o;
        }
    }

    __syncthreads();   // all stores executed block-wide
    if (flags && tid == 0) {
        __threadfence();                                  // device-scope release
        atomicAdd(flags + b * FLAGS_PER_B + tt, 1);       // publish (b, tt)
    }
}

// ---------------------------------------------------------------------------
// Scan body, round 7: 4 waves (1/SIMD), self-owned ballot, ONE barrier/step.
//   Phase 1: wave w = k-chunk [64w,64w+64); thread (w,l) holds
//   V[4l..4l+3][64w..64w+64) in 256 VGPRs and unpacks its OWN previous
//   ballot (wave w's phase-2 neurons are [64w,64w+64) = exactly its k-chunk;
//   the 64-bit mask lives in SGPRs, never in LDS). Scalar nibble-skip; per
//   bit an s_cselect'ed 1.0/0.0 feeds 4 v_fmac (sgpr operand).
//   Accumulation = round 2's exact order: per h, 4 accs over 16-k subchunks,
//   (a0+a1)+(a2+a3); phase-2 tree (p0+p1)+(p2+p3)+br.  [absmax 0.0 lineage]
//   Partials go through a DOUBLE-BUFFERED pbuf -> one __syncthreads per step.
//   Phase 2: thread h = neuron h (all 256 threads active), reduce, membrane
//   update (verbatim fp sequence), ballot -> SGPR state for next step.
//   vmem: proj loads + spike stores bursted 1 step in 8 (as round 6).
// ---------------------------------------------------------------------------
__device__ void scan_body(float* __restrict__ PO,
                          const float* __restrict__ V,
                          const float* __restrict__ brec,
                          int* flags, float* smem)
{
    float* pbuf0 = smem;           // [4][256] partials, buffer A
    float* pbuf1 = smem + 1024;    // buffer B

    const int b = blockIdx.x;
    const int tid = threadIdx.x;   // 0..255
    const int w = tid >> 6;        // wave = k-chunk index
    const int l = tid & 63;
    const int h0 = l << 2;         // phase-1 rows h0..h0+3

    // Vr[i][k] = V[h0+i][64w + k]  (256 VGPRs, one-time load)
    float Vr[4][64];
#pragma unroll
    for (int i = 0; i < 4; ++i) {
        const float4* vp = reinterpret_cast<const float4*>(V + (size_t)(h0 + i) * kH + (w << 6));
#pragma unroll
        for (int c = 0; c < 16; ++c) {
            const float4 v = vp[c];
            Vr[i][c * 4 + 0] = v.x; Vr[i][c * 4 + 1] = v.y;
            Vr[i][c * 4 + 2] = v.z; Vr[i][c * 4 + 3] = v.w;
        }
    }

    const float br = brec[tid];            // phase-2 neuron = tid
    float mem = 0.f, spk = 0.f;
    unsigned long long bm = 0ull;          // wave w's spike word (SGPR state)
    float* base = PO + (size_t)b * (size_t)kT * kH + tid;

    int* bflags = flags ? (flags + b * FLAGS_PER_B) : nullptr;

    float pb[TBURST], pb2[TBURST], sst[TBURST];
    if (bflags) wait_flag(bflags + 0);     // proj tile (b, t<128) ready
#pragma unroll
    for (int i = 0; i < TBURST; ++i) pb[i] = base[(size_t)i * kH];

    for (int tb = 0; tb < kT / TBURST; ++tb) {
#pragma unroll
        for (int ti = 0; ti < TBURST; ++ti) {
            const int t = tb * TBURST + ti;

            // ---- vmem burst (1 step in 8): store prev 8 spikes, load next 8
            if (ti == 0) {
                if (tb > 0) {
#pragma unroll
                    for (int i = 0; i < TBURST; ++i)
                        base[(size_t)((tb - 1) * TBURST + i) * kH] = sst[i];
                }
                const int nb = tb + 1;
                if (bflags && nb < (kT / TBURST) && (nb & 15) == 0)
                    wait_flag(bflags + (nb >> 4));         // next 128-step tile
#pragma unroll
                for (int i = 0; i < TBURST; ++i) {
                    int tt2 = nb * TBURST + i;
                    if (tt2 > kT - 1) tt2 = kT - 1;        // clamp (harmless)
                    pb2[i] = base[(size_t)tt2 * kH];
                }
            }

            float* pw = (t & 1) ? pbuf1 : pbuf0;

            // ---- phase 1: partials from OWN ballot (wave-uniform SGPRs)
            const uint32_t lo = (uint32_t)bm;
            const uint32_t hi = (uint32_t)(bm >> 32);
            float a[4][4];   // a[h-row][16k-subchunk], round-2 grouping
#pragma unroll
            for (int i = 0; i < 4; ++i)
#pragma unroll
                for (int s = 0; s < 4; ++s) a[i][s] = 0.f;

#pragma unroll
            for (int n = 0; n < 16; ++n) {
                const uint32_t nib = ((n < 8 ? lo : hi) >> ((n & 7) * 4)) & 0xFu;
                if (nib) {                   // scalar (wave-uniform) skip
                    const int s = n >> 2;    // accumulator = 16-k subchunk
#pragma unroll
                    for (int bit = 0; bit < 4; ++bit) {
                        const int k = n * 4 + bit;
                        const float bf = ((nib >> bit) & 1u) ? 1.0f : 0.0f;  // s_cselect
                        a[0][s] = fmaf(bf, Vr[0][k], a[0][s]);
                        a[1][s] = fmaf(bf, Vr[1][k], a[1][s]);
                        a[2][s] = fmaf(bf, Vr[2][k], a[2][s]);
                        a[3][s] = fmaf(bf, Vr[3][k], a[3][s]);
                    }
                }
            }
            float4 part;   // round-2 combine per h: (a0+a1)+(a2+a3)
            part.x = (a[0][0] + a[0][1]) + (a[0][2] + a[0][3]);
            part.y = (a[1][0] + a[1][1]) + (a[1][2] + a[1][3]);
            part.z = (a[2][0] + a[2][1]) + (a[2][2] + a[2][3]);
            part.w = (a[3][0] + a[3][1]) + (a[3][2] + a[3][3]);
            *reinterpret_cast<float4*>(pw + w * kH + h0) = part;

            __syncthreads();   // the ONLY barrier: partials visible

            // ---- phase 2 (all threads; neuron = tid): reduce + update
            {
                const float p0 = pw[0 * kH + tid];
                const float p1 = pw[1 * kH + tid];
                const float p2 = pw[2 * kH + tid];
                const float p3 = pw[3 * kH + tid];
                const float rec = ((p0 + p1) + (p2 + p3)) + br;  // round-2 tree
                const float pj = pb[ti];
                float m2;
                {
#pragma clang fp contract(off)
                    const float input_ = pj + spk;  // combined = proj + spk
                    m2 = kBeta * mem;               // reference op order
                    m2 = m2 + input_;
                    m2 = m2 + rec;
                    m2 = m2 - spk * kThr;           // reset == spk_prev exactly
                }
                const bool fire = (m2 > kThr);
                const float ns = fire ? 1.0f : 0.0f;
                bm = __ballot(fire);                // wave w's word w, in SGPRs
                mem = m2;
                spk = ns;
                sst[ti] = ns;                       // buffered; stored next burst
            }
            // no second barrier: next step writes the OTHER pbuf buffer
        }
#pragma unroll
        for (int i = 0; i < TBURST; ++i) pb[i] = pb2[i];
    }

    // final burst of spikes (t = kT-8 .. kT-1)
#pragma unroll
    for (int i = 0; i < TBURST; ++i)
        base[(size_t)((kT / TBURST - 1) * TBURST + i) * kH] = sst[i];
}

// ---------------------------------------------------------------------------
__global__ void __launch_bounds__(256, 1)
fused(const float* __restrict__ x, const float* __restrict__ W,
      const float* __restrict__ b_in, const float* __restrict__ V,
      const float* __restrict__ b_rec, float* __restrict__ PO,
      int* flags, int n_scan)
{
    __shared__ __align__(16) float smem[SMEM_FLOATS];
    if ((int)blockIdx.x < n_scan) {
        scan_body(PO, V, b_rec, flags, smem);
    } else {
        gemm_body(x, W, b_in, PO, flags, (int)blockIdx.x - n_scan, smem);
    }
}

// ---------------------------------------------------------------------------
extern "C" void kernel_launch(void* const* d_in, const int* in_sizes, int n_in,
                              void* d_out, int out_size, void* d_ws, size_t ws_size,
                              hipStream_t stream) {
    const float* x     = (const float*)d_in[0];
    const float* W_in  = (const float*)d_in[1];
    const float* b_in  = (const float*)d_in[2];
    const float* V     = (const float*)d_in[3];
    const float* b_rec = (const float*)d_in[4];
    float* out = (float*)d_out;

    const size_t flag_bytes = (size_t)kB * FLAGS_PER_B * sizeof(int);
    if (ws_size >= flag_bytes) {
        int* flags = (int*)d_ws;
        hipMemsetAsync(flags, 0, flag_bytes, stream);   // ws is poisoned 0xAA
        fused<<<N_SCAN + N_GEMM, 256, 0, stream>>>(x, W_in, b_in, V, b_rec,
                                                   out, flags, N_SCAN);
    } else {
        // fallback: sequential (no flags) — GEMM pass, then scan pass
        fused<<<N_GEMM, 256, 0, stream>>>(x, W_in, b_in, V, b_rec, out, nullptr, 0);
        fused<<<N_SCAN, 256, 0, stream>>>(x, W_in, b_in, V, b_rec, out, nullptr, N_SCAN);
    }
}